// Round 7
// baseline (949.498 us; speedup 1.0000x reference)
//
#include <hip/hip_runtime.h>
#include <math.h>
#include <stdint.h>

#define NN 100000
#define NE 1600000
#define GIN 128
#define GH 64
#define GOUT 10
#define NG 512
#define TPB 256
#define SCB 1024
#define NB ((NN + SCB - 1) / SCB)   // 98 scan blocks
#define MMBLK 512                   // blocks for MFMA matmuls
#define SPB 128                     // scatter blocks per XCD-part (grid = 8*SPB)
#define AGB 2048                    // agg blocks (grid); /8 -> 256 per XCD slot
#define NSB (AGB / 4)               // sub-blocks per feature-block ct (512)

typedef __attribute__((ext_vector_type(8))) short bf16x8;
typedef __attribute__((ext_vector_type(4))) float f32x4;

// ---- bf16 helpers (RNE pack) ----
__device__ __forceinline__ float bflo(uint32_t u) { return __uint_as_float(u << 16); }
__device__ __forceinline__ float bfhi(uint32_t u) { return __uint_as_float(u & 0xFFFF0000u); }
__device__ __forceinline__ uint32_t f2bf(float f) {
  uint32_t b = __float_as_uint(f);
  return (b + 0x7FFFu + ((b >> 16) & 1u)) >> 16;
}
__device__ __forceinline__ uint32_t pack2(float lo, float hi) { return f2bf(lo) | (f2bf(hi) << 16); }
__device__ __forceinline__ short bfs(float f) { return (short)f2bf(f); }

__global__ void k_zero_i(int* __restrict__ p, int n) {
  int i = blockIdx.x * TPB + threadIdx.x;
  if (i < n) p[i] = 0;
}

__global__ void k_hist(const int* __restrict__ col, int* __restrict__ deg) {
  int e = blockIdx.x * TPB + threadIdx.x;
  if (e < NE) atomicAdd(&deg[col[e]], 1);
}

__global__ void k_dinv(const int* __restrict__ deg, float* __restrict__ dinv) {
  int i = blockIdx.x * TPB + threadIdx.x;
  if (i < NN) dinv[i] = rsqrtf((float)deg[i] + 1.0f);  // +1 self-loop
}

// gstart[g] = first node index with batch >= g (batch sorted); gstart[NG] = NN
__global__ void k_gstart(const int* __restrict__ batch, int* __restrict__ gstart) {
  int g = blockIdx.x * TPB + threadIdx.x;
  if (g > NG) return;
  int lo = 0, hi = NN;
  while (lo < hi) { int mid = (lo + hi) >> 1; if (batch[mid] < g) lo = mid + 1; else hi = mid; }
  gstart[g] = lo;
}

__global__ void k_scan1(const int* __restrict__ deg, int* __restrict__ pref,
                        int* __restrict__ bsum) {
  __shared__ int wsum[8];
  int t = threadIdx.x;
  int base = blockIdx.x * SCB;
  int v[4]; int s = 0;
#pragma unroll
  for (int j = 0; j < 4; ++j) {
    int idx = base + t * 4 + j;
    v[j] = (idx < NN) ? deg[idx] : 0;
    s += v[j];
  }
  int lane = t & 63, wid = t >> 6;
  int sc = s;
#pragma unroll
  for (int off = 1; off < 64; off <<= 1) {
    int u = __shfl_up(sc, off);
    if (lane >= off) sc += u;
  }
  if (lane == 63) wsum[wid] = sc;
  __syncthreads();
  if (t == 0) {
    int a = 0;
    for (int w = 0; w < 4; ++w) { int x = wsum[w]; wsum[w] = a; a += x; }
  }
  __syncthreads();
  int excl = sc - s + wsum[wid];
#pragma unroll
  for (int j = 0; j < 4; ++j) {
    int idx = base + t * 4 + j;
    if (idx < NN) pref[idx] = excl;
    excl += v[j];
  }
  if (t == TPB - 1) bsum[blockIdx.x] = excl;  // block total
}

__global__ void k_scan2(int* __restrict__ bsum) {
  __shared__ int l[NB];
  int t = threadIdx.x;
  if (t < NB) l[t] = bsum[t];
  __syncthreads();
  if (t == 0) {
    int a = 0;
    for (int i = 0; i < NB; ++i) { int x = l[i]; l[i] = a; a += x; }
  }
  __syncthreads();
  if (t < NB) bsum[t] = l[t];
}

__global__ void k_scan3(const int* __restrict__ pref, const int* __restrict__ bsum,
                        int* __restrict__ rowptr, int* __restrict__ cursor) {
  int i = blockIdx.x * TPB + threadIdx.x;
  if (i < NN) {
    int v = pref[i] + bsum[i / SCB];
    rowptr[i] = v;
    cursor[i] = v;
  }
  if (i == NN) rowptr[NN] = NE;
}

// XCD-partitioned scatter: block handles only dsts in its 1/8 node range, so
// its esrc slice + cursors stay in one XCD's L2 and lines fill before writeback.
__global__ void k_scatter_p(const int* __restrict__ row, const int* __restrict__ col,
                            int* __restrict__ cursor, int* __restrict__ esrc) {
  int part = blockIdx.x & 7;
  int lo = part * (NN / 8), hi = lo + (NN / 8);
  for (int e = (blockIdx.x >> 3) * TPB + threadIdx.x; e < NE; e += SPB * TPB) {
    int c = col[e];
    if (c >= lo && c < hi) {
      int p = atomicAdd(&cursor[c], 1);
      esrc[p] = row[e];
    }
  }
}

// ---- MFMA matmul, layer 1: X f32 [NN,128] @ W1 -> blocked bf16 Y[4][NN][16], *dinv ----
__global__ __launch_bounds__(TPB, 1)
void k_mm1(const float* __restrict__ X, const float* __restrict__ W,
           const float* __restrict__ dinv, ushort* __restrict__ Y) {
  int lane = threadIdx.x & 63;
  int wv = blockIdx.x * (TPB / 64) + (threadIdx.x >> 6);
  const int nwv = MMBLK * (TPB / 64);
  int kb = (lane >> 4) * 8;
  int fcol = lane & 15;
  bf16x8 bfr[4][4];
#pragma unroll
  for (int kt = 0; kt < 4; ++kt)
#pragma unroll
    for (int ct = 0; ct < 4; ++ct)
#pragma unroll
      for (int j = 0; j < 8; ++j)
        bfr[kt][ct][j] = bfs(W[(size_t)(kt * 32 + kb + j) * GH + ct * 16 + fcol]);
  const int NT = NN / 16;
  for (int t = wv; t < NT; t += nwv) {
    int n0 = t * 16;
    const float* xr = X + (size_t)(n0 + fcol) * GIN;
    f32x4 acc[4] = {{0,0,0,0},{0,0,0,0},{0,0,0,0},{0,0,0,0}};
#pragma unroll
    for (int kt = 0; kt < 4; ++kt) {
      float4 p = *(const float4*)(xr + kt * 32 + kb);
      float4 q = *(const float4*)(xr + kt * 32 + kb + 4);
      bf16x8 a;
      a[0] = bfs(p.x); a[1] = bfs(p.y); a[2] = bfs(p.z); a[3] = bfs(p.w);
      a[4] = bfs(q.x); a[5] = bfs(q.y); a[6] = bfs(q.z); a[7] = bfs(q.w);
#pragma unroll
      for (int ct = 0; ct < 4; ++ct)
        acc[ct] = __builtin_amdgcn_mfma_f32_16x16x32_bf16(a, bfr[kt][ct], acc[ct], 0, 0, 0);
    }
    int rbase = (lane >> 4) * 4;
#pragma unroll
    for (int reg = 0; reg < 4; ++reg) {
      int n = n0 + rbase + reg;
      float d = dinv[n];
#pragma unroll
      for (int ct = 0; ct < 4; ++ct)
        Y[((size_t)ct * NN + n) * 16 + fcol] = (ushort)f2bf(acc[ct][reg] * d);
    }
  }
}

// ---- MFMA matmul, layers 2/3: blocked bf16 X[4][NN][16] @ W -> blocked bf16 Y, *dinv ----
__global__ __launch_bounds__(TPB, 1)
void k_mmh(const ushort* __restrict__ X, const float* __restrict__ W,
           const float* __restrict__ dinv, ushort* __restrict__ Y) {
  int lane = threadIdx.x & 63;
  int wv = blockIdx.x * (TPB / 64) + (threadIdx.x >> 6);
  const int nwv = MMBLK * (TPB / 64);
  int kb = (lane >> 4) * 8;
  int fcol = lane & 15;
  bf16x8 bfr[2][4];
#pragma unroll
  for (int kt = 0; kt < 2; ++kt)
#pragma unroll
    for (int ct = 0; ct < 4; ++ct)
#pragma unroll
      for (int j = 0; j < 8; ++j)
        bfr[kt][ct][j] = bfs(W[(size_t)(kt * 32 + kb + j) * GH + ct * 16 + fcol]);
  // A-frag source block/offset for k = kt*32 + kb + j:
  int abk = (lane >> 5);            // 0/1: block contribution from kb
  int aoff = ((lane >> 4) & 1) * 8; // 0/8 within block
  const int NT = NN / 16;
  for (int t = wv; t < NT; t += nwv) {
    int n0 = t * 16;
    f32x4 acc[4] = {{0,0,0,0},{0,0,0,0},{0,0,0,0},{0,0,0,0}};
#pragma unroll
    for (int kt = 0; kt < 2; ++kt) {
      bf16x8 a = *(const bf16x8*)(X + (((size_t)(kt * 2 + abk) * NN + n0 + fcol) * 16 + aoff));
#pragma unroll
      for (int ct = 0; ct < 4; ++ct)
        acc[ct] = __builtin_amdgcn_mfma_f32_16x16x32_bf16(a, bfr[kt][ct], acc[ct], 0, 0, 0);
    }
    int rbase = (lane >> 4) * 4;
#pragma unroll
    for (int reg = 0; reg < 4; ++reg) {
      int n = n0 + rbase + reg;
      float d = dinv[n];
#pragma unroll
      for (int ct = 0; ct < 4; ++ct)
        Y[((size_t)ct * NN + n) * 16 + fcol] = (ushort)f2bf(acc[ct][reg] * d);
    }
  }
}

// Feature-blocked aggregation. Grid = AGB blocks; ct = (blockIdx&7)>>1 so each
// XCD pair gathers only from its 3.2 MB sub-table (L2-resident). One wave per
// node per pass; 32 edge-slots x 2 lanes x 16B loads.
template<bool RELU, bool SCALE_SRC, bool BIAS>
__global__ void k_aggb(const int* __restrict__ rowptr, const int* __restrict__ esrc,
                       const float* __restrict__ dinv, const ushort* __restrict__ hp,
                       const float* __restrict__ bias, ushort* __restrict__ out) {
  int ct = (blockIdx.x & 7) >> 1;
  int sb = ((blockIdx.x >> 3) << 1) | (blockIdx.x & 1);   // 0..NSB-1
  int lane = threadIdx.x & 63;
  int slot = lane >> 1, h = lane & 1;
  const ushort* tbl = hp + (size_t)ct * NN * 16;
  ushort* ot = out + (size_t)ct * NN * 16;
  for (int n = sb * 4 + (threadIdx.x >> 6); n < NN; n += NSB * 4) {
    int s0 = rowptr[n], s1 = rowptr[n + 1];
    float acc[8] = {0.f, 0.f, 0.f, 0.f, 0.f, 0.f, 0.f, 0.f};
    for (int e = s0 + slot; e < s1; e += 32) {
      int r = esrc[e];
      uint4 v = *(const uint4*)(tbl + (size_t)r * 16 + h * 8);
      float d = SCALE_SRC ? dinv[r] : 1.f;
      acc[0] += bflo(v.x) * d; acc[1] += bfhi(v.x) * d;
      acc[2] += bflo(v.y) * d; acc[3] += bfhi(v.y) * d;
      acc[4] += bflo(v.z) * d; acc[5] += bfhi(v.z) * d;
      acc[6] += bflo(v.w) * d; acc[7] += bfhi(v.w) * d;
    }
#pragma unroll
    for (int off = 2; off < 64; off <<= 1) {
#pragma unroll
      for (int i = 0; i < 8; ++i) acc[i] += __shfl_xor(acc[i], off);
    }
    if (slot == 0) {  // lanes 0 (h=0) and 1 (h=1)
      float dn = dinv[n];
      uint4 sv = *(const uint4*)(tbl + (size_t)n * 16 + h * 8);
      float sc = SCALE_SRC ? dn : 1.f;
      float r8[8];
      r8[0] = (acc[0] + bflo(sv.x) * sc) * dn; r8[1] = (acc[1] + bfhi(sv.x) * sc) * dn;
      r8[2] = (acc[2] + bflo(sv.y) * sc) * dn; r8[3] = (acc[3] + bfhi(sv.y) * sc) * dn;
      r8[4] = (acc[4] + bflo(sv.z) * sc) * dn; r8[5] = (acc[5] + bfhi(sv.z) * sc) * dn;
      r8[6] = (acc[6] + bflo(sv.w) * sc) * dn; r8[7] = (acc[7] + bfhi(sv.w) * sc) * dn;
      if (BIAS) {
        const float* bp = bias + ct * 16 + h * 8;
        float4 bA = *(const float4*)bp, bB = *(const float4*)(bp + 4);
        r8[0] += bA.x; r8[1] += bA.y; r8[2] += bA.z; r8[3] += bA.w;
        r8[4] += bB.x; r8[5] += bB.y; r8[6] += bB.z; r8[7] += bB.w;
      }
      if (RELU) {
#pragma unroll
        for (int i = 0; i < 8; ++i) r8[i] = fmaxf(r8[i], 0.f);
      }
      uint4 o;
      o.x = pack2(r8[0], r8[1]); o.y = pack2(r8[2], r8[3]);
      o.z = pack2(r8[4], r8[5]); o.w = pack2(r8[6], r8[7]);
      *(uint4*)(ot + (size_t)n * 16 + h * 8) = o;
    }
  }
}

// per-graph segmented sum over sorted batch; input blocked [4][NN][16]
__global__ void k_pool(const ushort* __restrict__ agg4, const int* __restrict__ gstart,
                       float* __restrict__ P) {
  __shared__ float part[4][GH];
  int g = blockIdx.x;
  int f = threadIdx.x & 63, r = threadIdx.x >> 6;
  int blk = f >> 4, off = f & 15;
  const ushort* src = agg4 + (size_t)blk * NN * 16 + off;
  int a = gstart[g], b = gstart[g + 1];
  float acc = 0.f;
  for (int n = a + r; n < b; n += 4)
    acc += __uint_as_float(((uint32_t)src[(size_t)n * 16]) << 16);
  part[r][f] = acc;
  __syncthreads();
  if (r == 0) P[(size_t)g * GH + f] = part[0][f] + part[1][f] + part[2][f] + part[3][f];
}

__global__ void k_head(const float* __restrict__ P, const int* __restrict__ gstart,
                       const float* __restrict__ W4, const float* __restrict__ b4,
                       float* __restrict__ out) {
  int g = blockIdx.x;
  int lane = threadIdx.x;  // 64
  float c = fmaxf((float)(gstart[g + 1] - gstart[g]), 1.0f);
  float p = P[(size_t)g * GH + lane] / c;
  float t[GOUT];
#pragma unroll
  for (int j = 0; j < GOUT; ++j) {
    float r = p * W4[lane * GOUT + j];
#pragma unroll
    for (int off = 1; off < 64; off <<= 1) r += __shfl_xor(r, off);
    t[j] = r + b4[j];
  }
  if (lane == 0) {
    float mx = -1e30f;
#pragma unroll
    for (int j = 0; j < GOUT; ++j) mx = fmaxf(mx, t[j]);
    float sum = 0.f;
#pragma unroll
    for (int j = 0; j < GOUT; ++j) sum += expf(t[j] - mx);
    float lse = mx + logf(sum);
#pragma unroll
    for (int j = 0; j < GOUT; ++j) out[(size_t)g * GOUT + j] = t[j] - lse;
  }
}

static inline int cdiv(long a, long b) { return (int)((a + b - 1) / b); }

extern "C" void kernel_launch(void* const* d_in, const int* in_sizes, int n_in,
                              void* d_out, int out_size, void* d_ws, size_t ws_size,
                              hipStream_t stream) {
  const float* x  = (const float*)d_in[0];
  const int*   ei = (const int*)d_in[1];
  const int*   bt = (const int*)d_in[2];
  const float* W1 = (const float*)d_in[3];
  const float* b1 = (const float*)d_in[4];
  const float* W2 = (const float*)d_in[5];
  const float* b2 = (const float*)d_in[6];
  const float* W3 = (const float*)d_in[7];
  const float* b3 = (const float*)d_in[8];
  const float* W4 = (const float*)d_in[9];
  const float* b4 = (const float*)d_in[10];
  float* out = (float*)d_out;

  ushort* HP   = (ushort*)d_ws;                       // NN*64 bf16 (blocked [4][NN][16])
  ushort* ACT  = HP + (size_t)NN * GH;                // NN*64 bf16 (blocked)
  float* dinv  = (float*)(ACT + (size_t)NN * GH);     // NN
  float* P     = dinv + NN;                           // NG*64
  int* gstart  = (int*)(P + (size_t)NG * GH);         // NG+1
  int* deg     = gstart + NG + 3;                     // NN
  int* pref    = deg + NN;                            // NN
  int* rowptr  = pref + NN;                           // NN+1
  int* cursor  = rowptr + NN + 1;                     // NN
  int* bsum    = cursor + NN;                         // NB
  int* esrc    = bsum + ((NB + 3) & ~3);              // NE

  const int* row = ei;        // edge_index[0] = source
  const int* col = ei + NE;   // edge_index[1] = target (aggregate here)

  // --- CSR build + dinv + graph starts ---
  k_zero_i<<<cdiv(NN, TPB), TPB, 0, stream>>>(deg, NN);
  k_hist<<<cdiv(NE, TPB), TPB, 0, stream>>>(col, deg);
  k_dinv<<<cdiv(NN, TPB), TPB, 0, stream>>>(deg, dinv);
  k_gstart<<<cdiv(NG + 1, TPB), TPB, 0, stream>>>(bt, gstart);
  k_scan1<<<NB, TPB, 0, stream>>>(deg, pref, bsum);
  k_scan2<<<1, TPB, 0, stream>>>(bsum);
  k_scan3<<<cdiv(NN + 1, TPB), TPB, 0, stream>>>(pref, bsum, rowptr, cursor);
  k_scatter_p<<<8 * SPB, TPB, 0, stream>>>(row, col, cursor, esrc);

  // --- layer 1 ---
  k_mm1<<<MMBLK, TPB, 0, stream>>>(x, W1, dinv, HP);
  k_aggb<true, false, true><<<AGB, TPB, 0, stream>>>(rowptr, esrc, dinv, HP, b1, ACT);
  // --- layer 2 ---
  k_mmh<<<MMBLK, TPB, 0, stream>>>(ACT, W2, dinv, HP);
  k_aggb<true, false, true><<<AGB, TPB, 0, stream>>>(rowptr, esrc, dinv, HP, b2, ACT);
  // --- layer 3 ---
  k_mmh<<<MMBLK, TPB, 0, stream>>>(ACT, W3, dinv, HP);
  k_aggb<true, false, true><<<AGB, TPB, 0, stream>>>(rowptr, esrc, dinv, HP, b3, ACT);
  // --- layer 4 (algebraic swap): AGG4 = Â·H3 into HP, no bias/relu ---
  k_aggb<false, true, false><<<AGB, TPB, 0, stream>>>(rowptr, esrc, dinv, ACT, nullptr, HP);

  // --- pool + head ---
  k_pool<<<NG, TPB, 0, stream>>>(HP, gstart, P);
  k_head<<<NG, 64, 0, stream>>>(P, gstart, W4, b4, out);
}

// Round 8
// 474.212 us; speedup vs baseline: 2.0023x; 2.0023x over previous
//
#include <hip/hip_runtime.h>
#include <math.h>
#include <stdint.h>

#define NN 100000
#define NE 1600000
#define GIN 128
#define GH 64
#define GOUT 10
#define NG 512
#define TPB 256
#define SCB 1024
#define NB ((NN + SCB - 1) / SCB)   // 98 scan blocks
#define MMBLK 512                   // blocks for MFMA matmuls
#define SPB 128                     // scatter blocks per XCD-part (grid = 8*SPB)
#define AGB 2048                    // agg blocks; /8 -> 2 XCD-slots per feature block
#define NSB (AGB / 4)               // sub-blocks per feature-block ct (512)

typedef __attribute__((ext_vector_type(8))) short bf16x8;
typedef __attribute__((ext_vector_type(4))) float f32x4;

// ---- bf16 helpers (RNE pack) ----
__device__ __forceinline__ float bflo(uint32_t u) { return __uint_as_float(u << 16); }
__device__ __forceinline__ float bfhi(uint32_t u) { return __uint_as_float(u & 0xFFFF0000u); }
__device__ __forceinline__ uint32_t f2bf(float f) {
  uint32_t b = __float_as_uint(f);
  return (b + 0x7FFFu + ((b >> 16) & 1u)) >> 16;
}
__device__ __forceinline__ uint32_t pack2(float lo, float hi) { return f2bf(lo) | (f2bf(hi) << 16); }
__device__ __forceinline__ short bfs(float f) { return (short)f2bf(f); }

__global__ void k_zero_i(int* __restrict__ p, int n) {
  int i = blockIdx.x * TPB + threadIdx.x;
  if (i < n) p[i] = 0;
}

__global__ void k_hist(const int* __restrict__ col, int* __restrict__ deg) {
  int e = blockIdx.x * TPB + threadIdx.x;
  if (e < NE) atomicAdd(&deg[col[e]], 1);
}

__global__ void k_dinv(const int* __restrict__ deg, float* __restrict__ dinv) {
  int i = blockIdx.x * TPB + threadIdx.x;
  if (i < NN) dinv[i] = rsqrtf((float)deg[i] + 1.0f);  // +1 self-loop
}

// gstart[g] = first node index with batch >= g (batch sorted); gstart[NG] = NN
__global__ void k_gstart(const int* __restrict__ batch, int* __restrict__ gstart) {
  int g = blockIdx.x * TPB + threadIdx.x;
  if (g > NG) return;
  int lo = 0, hi = NN;
  while (lo < hi) { int mid = (lo + hi) >> 1; if (batch[mid] < g) lo = mid + 1; else hi = mid; }
  gstart[g] = lo;
}

__global__ void k_scan1(const int* __restrict__ deg, int* __restrict__ pref,
                        int* __restrict__ bsum) {
  __shared__ int wsum[8];
  int t = threadIdx.x;
  int base = blockIdx.x * SCB;
  int v[4]; int s = 0;
#pragma unroll
  for (int j = 0; j < 4; ++j) {
    int idx = base + t * 4 + j;
    v[j] = (idx < NN) ? deg[idx] : 0;
    s += v[j];
  }
  int lane = t & 63, wid = t >> 6;
  int sc = s;
#pragma unroll
  for (int off = 1; off < 64; off <<= 1) {
    int u = __shfl_up(sc, off);
    if (lane >= off) sc += u;
  }
  if (lane == 63) wsum[wid] = sc;
  __syncthreads();
  if (t == 0) {
    int a = 0;
    for (int w = 0; w < 4; ++w) { int x = wsum[w]; wsum[w] = a; a += x; }
  }
  __syncthreads();
  int excl = sc - s + wsum[wid];
#pragma unroll
  for (int j = 0; j < 4; ++j) {
    int idx = base + t * 4 + j;
    if (idx < NN) pref[idx] = excl;
    excl += v[j];
  }
  if (t == TPB - 1) bsum[blockIdx.x] = excl;  // block total
}

__global__ void k_scan2(int* __restrict__ bsum) {
  __shared__ int l[NB];
  int t = threadIdx.x;
  if (t < NB) l[t] = bsum[t];
  __syncthreads();
  if (t == 0) {
    int a = 0;
    for (int i = 0; i < NB; ++i) { int x = l[i]; l[i] = a; a += x; }
  }
  __syncthreads();
  if (t < NB) bsum[t] = l[t];
}

__global__ void k_scan3(const int* __restrict__ pref, const int* __restrict__ bsum,
                        int* __restrict__ rowptr, int* __restrict__ cursor) {
  int i = blockIdx.x * TPB + threadIdx.x;
  if (i < NN) {
    int v = pref[i] + bsum[i / SCB];
    rowptr[i] = v;
    cursor[i] = v;
  }
  if (i == NN) rowptr[NN] = NE;
}

// XCD-partitioned scatter: block handles only dsts in its 1/8 node range.
__global__ void k_scatter_p(const int* __restrict__ row, const int* __restrict__ col,
                            int* __restrict__ cursor, int* __restrict__ esrc) {
  int part = blockIdx.x & 7;
  int lo = part * (NN / 8), hi = lo + (NN / 8);
  for (int e = (blockIdx.x >> 3) * TPB + threadIdx.x; e < NE; e += SPB * TPB) {
    int c = col[e];
    if (c >= lo && c < hi) {
      int p = atomicAdd(&cursor[c], 1);
      esrc[p] = row[e];
    }
  }
}

// ---- MFMA matmul, layer 1: X f32 [NN,128] @ W1 -> blocked bf16 Y[4][NN][16], *dinv ----
__global__ __launch_bounds__(TPB, 1)
void k_mm1(const float* __restrict__ X, const float* __restrict__ W,
           const float* __restrict__ dinv, ushort* __restrict__ Y) {
  int lane = threadIdx.x & 63;
  int wv = blockIdx.x * (TPB / 64) + (threadIdx.x >> 6);
  const int nwv = MMBLK * (TPB / 64);
  int kb = (lane >> 4) * 8;
  int fcol = lane & 15;
  bf16x8 bfr[4][4];
#pragma unroll
  for (int kt = 0; kt < 4; ++kt)
#pragma unroll
    for (int ct = 0; ct < 4; ++ct)
#pragma unroll
      for (int j = 0; j < 8; ++j)
        bfr[kt][ct][j] = bfs(W[(size_t)(kt * 32 + kb + j) * GH + ct * 16 + fcol]);
  const int NT = NN / 16;
  for (int t = wv; t < NT; t += nwv) {
    int n0 = t * 16;
    const float* xr = X + (size_t)(n0 + fcol) * GIN;
    f32x4 acc[4] = {{0,0,0,0},{0,0,0,0},{0,0,0,0},{0,0,0,0}};
#pragma unroll
    for (int kt = 0; kt < 4; ++kt) {
      float4 p = *(const float4*)(xr + kt * 32 + kb);
      float4 q = *(const float4*)(xr + kt * 32 + kb + 4);
      bf16x8 a;
      a[0] = bfs(p.x); a[1] = bfs(p.y); a[2] = bfs(p.z); a[3] = bfs(p.w);
      a[4] = bfs(q.x); a[5] = bfs(q.y); a[6] = bfs(q.z); a[7] = bfs(q.w);
#pragma unroll
      for (int ct = 0; ct < 4; ++ct)
        acc[ct] = __builtin_amdgcn_mfma_f32_16x16x32_bf16(a, bfr[kt][ct], acc[ct], 0, 0, 0);
    }
    int rbase = (lane >> 4) * 4;
#pragma unroll
    for (int reg = 0; reg < 4; ++reg) {
      int n = n0 + rbase + reg;
      float d = dinv[n];
#pragma unroll
      for (int ct = 0; ct < 4; ++ct)
        Y[((size_t)ct * NN + n) * 16 + fcol] = (ushort)f2bf(acc[ct][reg] * d);
    }
  }
}

// ---- MFMA matmul, layers 2/3: blocked bf16 X[4][NN][16] @ W -> blocked bf16 Y, *dinv ----
__global__ __launch_bounds__(TPB, 1)
void k_mmh(const ushort* __restrict__ X, const float* __restrict__ W,
           const float* __restrict__ dinv, ushort* __restrict__ Y) {
  int lane = threadIdx.x & 63;
  int wv = blockIdx.x * (TPB / 64) + (threadIdx.x >> 6);
  const int nwv = MMBLK * (TPB / 64);
  int kb = (lane >> 4) * 8;
  int fcol = lane & 15;
  bf16x8 bfr[2][4];
#pragma unroll
  for (int kt = 0; kt < 2; ++kt)
#pragma unroll
    for (int ct = 0; ct < 4; ++ct)
#pragma unroll
      for (int j = 0; j < 8; ++j)
        bfr[kt][ct][j] = bfs(W[(size_t)(kt * 32 + kb + j) * GH + ct * 16 + fcol]);
  int abk = (lane >> 5);            // block contribution from kb
  int aoff = ((lane >> 4) & 1) * 8; // 0/8 within block
  const int NT = NN / 16;
  for (int t = wv; t < NT; t += nwv) {
    int n0 = t * 16;
    f32x4 acc[4] = {{0,0,0,0},{0,0,0,0},{0,0,0,0},{0,0,0,0}};
#pragma unroll
    for (int kt = 0; kt < 2; ++kt) {
      bf16x8 a = *(const bf16x8*)(X + (((size_t)(kt * 2 + abk) * NN + n0 + fcol) * 16 + aoff));
#pragma unroll
      for (int ct = 0; ct < 4; ++ct)
        acc[ct] = __builtin_amdgcn_mfma_f32_16x16x32_bf16(a, bfr[kt][ct], acc[ct], 0, 0, 0);
    }
    int rbase = (lane >> 4) * 4;
#pragma unroll
    for (int reg = 0; reg < 4; ++reg) {
      int n = n0 + rbase + reg;
      float d = dinv[n];
#pragma unroll
      for (int ct = 0; ct < 4; ++ct)
        Y[((size_t)ct * NN + n) * 16 + fcol] = (ushort)f2bf(acc[ct][reg] * d);
    }
  }
}

// Feature-blocked aggregation v2: ct = (blockIdx&7)>>1 (3.2MB sub-table per XCD
// pair). 2 lanes own one node (h = lane&1 -> 8 feats each); 32 consecutive
// nodes per wave; register accumulation, NO cross-lane reduce; all lanes write.
template<bool RELU, bool SCALE_SRC, bool BIAS>
__global__ void k_aggb2(const int* __restrict__ rowptr, const int* __restrict__ esrc,
                        const float* __restrict__ dinv, const ushort* __restrict__ hp,
                        const float* __restrict__ bias, ushort* __restrict__ out) {
  int ct = (blockIdx.x & 7) >> 1;
  int sub = ((blockIdx.x >> 3) << 1) | (blockIdx.x & 1);   // 0..NSB-1
  int lane = threadIdx.x & 63;
  int h = lane & 1;
  const ushort* tbl = hp + (size_t)ct * NN * 16;
  ushort* ot = out + (size_t)ct * NN * 16;
  const int NGRP = NN / 32;  // 3125 groups of 32 nodes
  for (int g = sub * 4 + (threadIdx.x >> 6); g < NGRP; g += NSB * 4) {
    int n = g * 32 + (lane >> 1);
    int s0 = rowptr[n], s1 = rowptr[n + 1];
    float acc[8] = {0.f, 0.f, 0.f, 0.f, 0.f, 0.f, 0.f, 0.f};
    int e = s0;
    for (; e + 1 < s1; e += 2) {
      int r0 = esrc[e], r1 = esrc[e + 1];
      uint4 v0 = *(const uint4*)(tbl + (size_t)r0 * 16 + h * 8);
      uint4 v1 = *(const uint4*)(tbl + (size_t)r1 * 16 + h * 8);
      float d0 = 1.f, d1 = 1.f;
      if (SCALE_SRC) { d0 = dinv[r0]; d1 = dinv[r1]; }
      acc[0] += bflo(v0.x) * d0; acc[1] += bfhi(v0.x) * d0;
      acc[2] += bflo(v0.y) * d0; acc[3] += bfhi(v0.y) * d0;
      acc[4] += bflo(v0.z) * d0; acc[5] += bfhi(v0.z) * d0;
      acc[6] += bflo(v0.w) * d0; acc[7] += bfhi(v0.w) * d0;
      acc[0] += bflo(v1.x) * d1; acc[1] += bfhi(v1.x) * d1;
      acc[2] += bflo(v1.y) * d1; acc[3] += bfhi(v1.y) * d1;
      acc[4] += bflo(v1.z) * d1; acc[5] += bfhi(v1.z) * d1;
      acc[6] += bflo(v1.w) * d1; acc[7] += bfhi(v1.w) * d1;
    }
    if (e < s1) {
      int r = esrc[e];
      uint4 v = *(const uint4*)(tbl + (size_t)r * 16 + h * 8);
      float d = SCALE_SRC ? dinv[r] : 1.f;
      acc[0] += bflo(v.x) * d; acc[1] += bfhi(v.x) * d;
      acc[2] += bflo(v.y) * d; acc[3] += bfhi(v.y) * d;
      acc[4] += bflo(v.z) * d; acc[5] += bfhi(v.z) * d;
      acc[6] += bflo(v.w) * d; acc[7] += bfhi(v.w) * d;
    }
    float dn = dinv[n];
    uint4 sv = *(const uint4*)(tbl + (size_t)n * 16 + h * 8);
    float sc = SCALE_SRC ? dn : 1.f;
    float r8[8];
    r8[0] = (acc[0] + bflo(sv.x) * sc) * dn; r8[1] = (acc[1] + bfhi(sv.x) * sc) * dn;
    r8[2] = (acc[2] + bflo(sv.y) * sc) * dn; r8[3] = (acc[3] + bfhi(sv.y) * sc) * dn;
    r8[4] = (acc[4] + bflo(sv.z) * sc) * dn; r8[5] = (acc[5] + bfhi(sv.z) * sc) * dn;
    r8[6] = (acc[6] + bflo(sv.w) * sc) * dn; r8[7] = (acc[7] + bfhi(sv.w) * sc) * dn;
    if (BIAS) {
      const float* bp = bias + ct * 16 + h * 8;
      float4 bA = *(const float4*)bp, bB = *(const float4*)(bp + 4);
      r8[0] += bA.x; r8[1] += bA.y; r8[2] += bA.z; r8[3] += bA.w;
      r8[4] += bB.x; r8[5] += bB.y; r8[6] += bB.z; r8[7] += bB.w;
    }
    if (RELU) {
#pragma unroll
      for (int i = 0; i < 8; ++i) r8[i] = fmaxf(r8[i], 0.f);
    }
    uint4 o;
    o.x = pack2(r8[0], r8[1]); o.y = pack2(r8[2], r8[3]);
    o.z = pack2(r8[4], r8[5]); o.w = pack2(r8[6], r8[7]);
    *(uint4*)(ot + (size_t)n * 16 + h * 8) = o;
  }
}

// per-graph segmented sum over sorted batch; input blocked [4][NN][16]
__global__ void k_pool(const ushort* __restrict__ agg4, const int* __restrict__ gstart,
                       float* __restrict__ P) {
  __shared__ float part[4][GH];
  int g = blockIdx.x;
  int f = threadIdx.x & 63, r = threadIdx.x >> 6;
  int blk = f >> 4, off = f & 15;
  const ushort* src = agg4 + (size_t)blk * NN * 16 + off;
  int a = gstart[g], b = gstart[g + 1];
  float acc = 0.f;
  for (int n = a + r; n < b; n += 4)
    acc += __uint_as_float(((uint32_t)src[(size_t)n * 16]) << 16);
  part[r][f] = acc;
  __syncthreads();
  if (r == 0) P[(size_t)g * GH + f] = part[0][f] + part[1][f] + part[2][f] + part[3][f];
}

__global__ void k_head(const float* __restrict__ P, const int* __restrict__ gstart,
                       const float* __restrict__ W4, const float* __restrict__ b4,
                       float* __restrict__ out) {
  int g = blockIdx.x;
  int lane = threadIdx.x;  // 64
  float c = fmaxf((float)(gstart[g + 1] - gstart[g]), 1.0f);
  float p = P[(size_t)g * GH + lane] / c;
  float t[GOUT];
#pragma unroll
  for (int j = 0; j < GOUT; ++j) {
    float r = p * W4[lane * GOUT + j];
#pragma unroll
    for (int off = 1; off < 64; off <<= 1) r += __shfl_xor(r, off);
    t[j] = r + b4[j];
  }
  if (lane == 0) {
    float mx = -1e30f;
#pragma unroll
    for (int j = 0; j < GOUT; ++j) mx = fmaxf(mx, t[j]);
    float sum = 0.f;
#pragma unroll
    for (int j = 0; j < GOUT; ++j) sum += expf(t[j] - mx);
    float lse = mx + logf(sum);
#pragma unroll
    for (int j = 0; j < GOUT; ++j) out[(size_t)g * GOUT + j] = t[j] - lse;
  }
}

static inline int cdiv(long a, long b) { return (int)((a + b - 1) / b); }

extern "C" void kernel_launch(void* const* d_in, const int* in_sizes, int n_in,
                              void* d_out, int out_size, void* d_ws, size_t ws_size,
                              hipStream_t stream) {
  const float* x  = (const float*)d_in[0];
  const int*   ei = (const int*)d_in[1];
  const int*   bt = (const int*)d_in[2];
  const float* W1 = (const float*)d_in[3];
  const float* b1 = (const float*)d_in[4];
  const float* W2 = (const float*)d_in[5];
  const float* b2 = (const float*)d_in[6];
  const float* W3 = (const float*)d_in[7];
  const float* b3 = (const float*)d_in[8];
  const float* W4 = (const float*)d_in[9];
  const float* b4 = (const float*)d_in[10];
  float* out = (float*)d_out;

  ushort* HP   = (ushort*)d_ws;                       // NN*64 bf16 (blocked [4][NN][16])
  ushort* ACT  = HP + (size_t)NN * GH;                // NN*64 bf16 (blocked)
  float* dinv  = (float*)(ACT + (size_t)NN * GH);     // NN
  float* P     = dinv + NN;                           // NG*64
  int* gstart  = (int*)(P + (size_t)NG * GH);         // NG+1
  int* deg     = gstart + NG + 3;                     // NN
  int* pref    = deg + NN;                            // NN
  int* rowptr  = pref + NN;                           // NN+1
  int* cursor  = rowptr + NN + 1;                     // NN
  int* bsum    = cursor + NN;                         // NB
  int* esrc    = bsum + ((NB + 3) & ~3);              // NE

  const int* row = ei;        // edge_index[0] = source
  const int* col = ei + NE;   // edge_index[1] = target (aggregate here)

  // --- CSR build + dinv + graph starts ---
  k_zero_i<<<cdiv(NN, TPB), TPB, 0, stream>>>(deg, NN);
  k_hist<<<cdiv(NE, TPB), TPB, 0, stream>>>(col, deg);
  k_dinv<<<cdiv(NN, TPB), TPB, 0, stream>>>(deg, dinv);
  k_gstart<<<cdiv(NG + 1, TPB), TPB, 0, stream>>>(bt, gstart);
  k_scan1<<<NB, TPB, 0, stream>>>(deg, pref, bsum);
  k_scan2<<<1, TPB, 0, stream>>>(bsum);
  k_scan3<<<cdiv(NN + 1, TPB), TPB, 0, stream>>>(pref, bsum, rowptr, cursor);
  k_scatter_p<<<8 * SPB, TPB, 0, stream>>>(row, col, cursor, esrc);

  // --- layer 1 ---
  k_mm1<<<MMBLK, TPB, 0, stream>>>(x, W1, dinv, HP);
  k_aggb2<true, false, true><<<AGB, TPB, 0, stream>>>(rowptr, esrc, dinv, HP, b1, ACT);
  // --- layer 2 ---
  k_mmh<<<MMBLK, TPB, 0, stream>>>(ACT, W2, dinv, HP);
  k_aggb2<true, false, true><<<AGB, TPB, 0, stream>>>(rowptr, esrc, dinv, HP, b2, ACT);
  // --- layer 3 ---
  k_mmh<<<MMBLK, TPB, 0, stream>>>(ACT, W3, dinv, HP);
  k_aggb2<true, false, true><<<AGB, TPB, 0, stream>>>(rowptr, esrc, dinv, HP, b3, ACT);
  // --- layer 4 (algebraic swap): AGG4 = Â·H3 into HP, no bias/relu ---
  k_aggb2<false, true, false><<<AGB, TPB, 0, stream>>>(rowptr, esrc, dinv, ACT, nullptr, HP);

  // --- pool + head ---
  k_pool<<<NG, TPB, 0, stream>>>(HP, gstart, P);
  k_head<<<NG, 64, 0, stream>>>(P, gstart, W4, b4, out);
}

// Round 9
// 395.340 us; speedup vs baseline: 2.4017x; 1.1995x over previous
//
#include <hip/hip_runtime.h>
#include <math.h>
#include <stdint.h>

#define NN 100000
#define NE 1600000
#define GIN 128
#define GH 64
#define GOUT 10
#define NG 512
#define TPB 256
#define SCB 1024
#define NB ((NN + SCB - 1) / SCB)   // 98 scan blocks
#define MMBLK 1024                  // blocks for MFMA matmuls (4096 waves)
#define SPB 128                     // scatter blocks per XCD-part (grid = 8*SPB)

typedef __attribute__((ext_vector_type(8))) short bf16x8;
typedef __attribute__((ext_vector_type(4))) float f32x4;

// ---- bf16 helpers (RNE pack) ----
__device__ __forceinline__ float bflo(uint32_t u) { return __uint_as_float(u << 16); }
__device__ __forceinline__ float bfhi(uint32_t u) { return __uint_as_float(u & 0xFFFF0000u); }
__device__ __forceinline__ uint32_t f2bf(float f) {
  uint32_t b = __float_as_uint(f);
  return (b + 0x7FFFu + ((b >> 16) & 1u)) >> 16;
}
__device__ __forceinline__ uint32_t pack2(float lo, float hi) { return f2bf(lo) | (f2bf(hi) << 16); }
__device__ __forceinline__ short bfs(float f) { return (short)f2bf(f); }

__global__ void k_zero_i(int* __restrict__ p, int n) {
  int i = blockIdx.x * TPB + threadIdx.x;
  if (i < n) p[i] = 0;
}

__global__ void k_hist(const int* __restrict__ col, int* __restrict__ deg) {
  int e = blockIdx.x * TPB + threadIdx.x;
  if (e < NE) atomicAdd(&deg[col[e]], 1);
}

__global__ void k_dinv(const int* __restrict__ deg, float* __restrict__ dinv) {
  int i = blockIdx.x * TPB + threadIdx.x;
  if (i < NN) dinv[i] = rsqrtf((float)deg[i] + 1.0f);  // +1 self-loop
}

// gstart[g] = first node index with batch >= g (batch sorted); gstart[NG] = NN
__global__ void k_gstart(const int* __restrict__ batch, int* __restrict__ gstart) {
  int g = blockIdx.x * TPB + threadIdx.x;
  if (g > NG) return;
  int lo = 0, hi = NN;
  while (lo < hi) { int mid = (lo + hi) >> 1; if (batch[mid] < g) lo = mid + 1; else hi = mid; }
  gstart[g] = lo;
}

__global__ void k_scan1(const int* __restrict__ deg, int* __restrict__ pref,
                        int* __restrict__ bsum) {
  __shared__ int wsum[8];
  int t = threadIdx.x;
  int base = blockIdx.x * SCB;
  int v[4]; int s = 0;
#pragma unroll
  for (int j = 0; j < 4; ++j) {
    int idx = base + t * 4 + j;
    v[j] = (idx < NN) ? deg[idx] : 0;
    s += v[j];
  }
  int lane = t & 63, wid = t >> 6;
  int sc = s;
#pragma unroll
  for (int off = 1; off < 64; off <<= 1) {
    int u = __shfl_up(sc, off);
    if (lane >= off) sc += u;
  }
  if (lane == 63) wsum[wid] = sc;
  __syncthreads();
  if (t == 0) {
    int a = 0;
    for (int w = 0; w < 4; ++w) { int x = wsum[w]; wsum[w] = a; a += x; }
  }
  __syncthreads();
  int excl = sc - s + wsum[wid];
#pragma unroll
  for (int j = 0; j < 4; ++j) {
    int idx = base + t * 4 + j;
    if (idx < NN) pref[idx] = excl;
    excl += v[j];
  }
  if (t == TPB - 1) bsum[blockIdx.x] = excl;  // block total
}

__global__ void k_scan2(int* __restrict__ bsum) {
  __shared__ int l[NB];
  int t = threadIdx.x;
  if (t < NB) l[t] = bsum[t];
  __syncthreads();
  if (t == 0) {
    int a = 0;
    for (int i = 0; i < NB; ++i) { int x = l[i]; l[i] = a; a += x; }
  }
  __syncthreads();
  if (t < NB) bsum[t] = l[t];
}

__global__ void k_scan3(const int* __restrict__ pref, const int* __restrict__ bsum,
                        int* __restrict__ rowptr, int* __restrict__ cursor) {
  int i = blockIdx.x * TPB + threadIdx.x;
  if (i < NN) {
    int v = pref[i] + bsum[i / SCB];
    rowptr[i] = v;
    cursor[i] = v;
  }
  if (i == NN) rowptr[NN] = NE;
}

// XCD-partitioned scatter: block handles only dsts in its 1/8 node range, so
// its esrc slice + cursors stay hot in one L2 and lines fill before writeback.
__global__ void k_scatter_p(const int* __restrict__ row, const int* __restrict__ col,
                            int* __restrict__ cursor, int* __restrict__ esrc) {
  int part = blockIdx.x & 7;
  int lo = part * (NN / 8), hi = lo + (NN / 8);
  for (int e = (blockIdx.x >> 3) * TPB + threadIdx.x; e < NE; e += SPB * TPB) {
    int c = col[e];
    if (c >= lo && c < hi) {
      int p = atomicAdd(&cursor[c], 1);
      esrc[p] = row[e];
    }
  }
}

// ---- MFMA matmul, layer 1: X f32 [NN,128] @ W1[128,64] -> bf16 Y [NN,64], *dinv ----
__global__ __launch_bounds__(TPB, 1)
void k_mm1(const float* __restrict__ X, const float* __restrict__ W,
           const float* __restrict__ dinv, ushort* __restrict__ Y) {
  int lane = threadIdx.x & 63;
  int wv = blockIdx.x * (TPB / 64) + (threadIdx.x >> 6);
  const int nwv = MMBLK * (TPB / 64);
  int kb = (lane >> 4) * 8;   // k-base within a 32-k tile
  int fcol = lane & 15;       // B col / C col / A row index
  bf16x8 bfr[4][4];
#pragma unroll
  for (int kt = 0; kt < 4; ++kt)
#pragma unroll
    for (int ct = 0; ct < 4; ++ct)
#pragma unroll
      for (int j = 0; j < 8; ++j)
        bfr[kt][ct][j] = bfs(W[(size_t)(kt * 32 + kb + j) * GH + ct * 16 + fcol]);
  const int NT = NN / 16;  // 6250
  for (int t = wv; t < NT; t += nwv) {
    int n0 = t * 16;
    const float* xr = X + (size_t)(n0 + fcol) * GIN;
    f32x4 acc[4] = {{0,0,0,0},{0,0,0,0},{0,0,0,0},{0,0,0,0}};
#pragma unroll
    for (int kt = 0; kt < 4; ++kt) {
      float4 p = *(const float4*)(xr + kt * 32 + kb);
      float4 q = *(const float4*)(xr + kt * 32 + kb + 4);
      bf16x8 a;
      a[0] = bfs(p.x); a[1] = bfs(p.y); a[2] = bfs(p.z); a[3] = bfs(p.w);
      a[4] = bfs(q.x); a[5] = bfs(q.y); a[6] = bfs(q.z); a[7] = bfs(q.w);
#pragma unroll
      for (int ct = 0; ct < 4; ++ct)
        acc[ct] = __builtin_amdgcn_mfma_f32_16x16x32_bf16(a, bfr[kt][ct], acc[ct], 0, 0, 0);
    }
    int rbase = (lane >> 4) * 4;
#pragma unroll
    for (int reg = 0; reg < 4; ++reg) {
      int n = n0 + rbase + reg;
      float d = dinv[n];
#pragma unroll
      for (int ct = 0; ct < 4; ++ct)
        Y[(size_t)n * GH + ct * 16 + fcol] = (ushort)f2bf(acc[ct][reg] * d);
    }
  }
}

// ---- MFMA matmul, layers 2/3: X bf16 [NN,64] @ W[64,64] -> bf16 Y, *dinv ----
__global__ __launch_bounds__(TPB, 1)
void k_mmh(const ushort* __restrict__ X, const float* __restrict__ W,
           const float* __restrict__ dinv, ushort* __restrict__ Y) {
  int lane = threadIdx.x & 63;
  int wv = blockIdx.x * (TPB / 64) + (threadIdx.x >> 6);
  const int nwv = MMBLK * (TPB / 64);
  int kb = (lane >> 4) * 8;
  int fcol = lane & 15;
  bf16x8 bfr[2][4];
#pragma unroll
  for (int kt = 0; kt < 2; ++kt)
#pragma unroll
    for (int ct = 0; ct < 4; ++ct)
#pragma unroll
      for (int j = 0; j < 8; ++j)
        bfr[kt][ct][j] = bfs(W[(size_t)(kt * 32 + kb + j) * GH + ct * 16 + fcol]);
  const int NT = NN / 16;
  for (int t = wv; t < NT; t += nwv) {
    int n0 = t * 16;
    const ushort* xr = X + (size_t)(n0 + fcol) * GH;
    f32x4 acc[4] = {{0,0,0,0},{0,0,0,0},{0,0,0,0},{0,0,0,0}};
#pragma unroll
    for (int kt = 0; kt < 2; ++kt) {
      bf16x8 a = *(const bf16x8*)(xr + kt * 32 + kb);
#pragma unroll
      for (int ct = 0; ct < 4; ++ct)
        acc[ct] = __builtin_amdgcn_mfma_f32_16x16x32_bf16(a, bfr[kt][ct], acc[ct], 0, 0, 0);
    }
    int rbase = (lane >> 4) * 4;
#pragma unroll
    for (int reg = 0; reg < 4; ++reg) {
      int n = n0 + rbase + reg;
      float d = dinv[n];
#pragma unroll
      for (int ct = 0; ct < 4; ++ct)
        Y[(size_t)n * GH + ct * 16 + fcol] = (ushort)f2bf(acc[ct][reg] * d);
    }
  }
}

// One wave per node; 8 groups of 8 lanes; group q handles edges s0+q, s0+q+8, ...
// Each lane loads uint4 = 8 bf16 feats (full 128 B row per 8-lane group = one
// cache line, zero overfetch). acc f32; cross-group shfl reduction.
template<bool RELU, bool SCALE_SRC, bool BIAS>
__global__ void k_agg(const int* __restrict__ rowptr, const int* __restrict__ esrc,
                      const float* __restrict__ dinv, const uint4* __restrict__ hp,
                      const float* __restrict__ bias, uint4* __restrict__ out) {
  int n = blockIdx.x * (TPB / 64) + (threadIdx.x >> 6);
  if (n >= NN) return;
  int lane = threadIdx.x & 63;
  int qid = lane >> 3, fq = lane & 7;
  int s0 = rowptr[n], s1 = rowptr[n + 1];
  float acc[8] = {0.f, 0.f, 0.f, 0.f, 0.f, 0.f, 0.f, 0.f};
  int e = s0 + qid;
  for (; e + 8 < s1; e += 16) {
    int r0 = esrc[e], r1 = esrc[e + 8];
    uint4 v0 = hp[(size_t)r0 * 8 + fq];
    uint4 v1 = hp[(size_t)r1 * 8 + fq];
    float d0 = 1.f, d1 = 1.f;
    if (SCALE_SRC) { d0 = dinv[r0]; d1 = dinv[r1]; }
    acc[0] += bflo(v0.x) * d0; acc[1] += bfhi(v0.x) * d0;
    acc[2] += bflo(v0.y) * d0; acc[3] += bfhi(v0.y) * d0;
    acc[4] += bflo(v0.z) * d0; acc[5] += bfhi(v0.z) * d0;
    acc[6] += bflo(v0.w) * d0; acc[7] += bfhi(v0.w) * d0;
    acc[0] += bflo(v1.x) * d1; acc[1] += bfhi(v1.x) * d1;
    acc[2] += bflo(v1.y) * d1; acc[3] += bfhi(v1.y) * d1;
    acc[4] += bflo(v1.z) * d1; acc[5] += bfhi(v1.z) * d1;
    acc[6] += bflo(v1.w) * d1; acc[7] += bfhi(v1.w) * d1;
  }
  if (e < s1) {
    int r = esrc[e];
    uint4 v = hp[(size_t)r * 8 + fq];
    float d = SCALE_SRC ? dinv[r] : 1.f;
    acc[0] += bflo(v.x) * d; acc[1] += bfhi(v.x) * d;
    acc[2] += bflo(v.y) * d; acc[3] += bfhi(v.y) * d;
    acc[4] += bflo(v.z) * d; acc[5] += bfhi(v.z) * d;
    acc[6] += bflo(v.w) * d; acc[7] += bfhi(v.w) * d;
  }
#pragma unroll
  for (int off = 8; off < 64; off <<= 1) {
#pragma unroll
    for (int i = 0; i < 8; ++i) acc[i] += __shfl_xor(acc[i], off);
  }
  if (qid == 0) {
    float dn = dinv[n];
    uint4 sv = hp[(size_t)n * 8 + fq];
    float sc = SCALE_SRC ? dn : 1.f;
    float r[8];
    r[0] = (acc[0] + bflo(sv.x) * sc) * dn; r[1] = (acc[1] + bfhi(sv.x) * sc) * dn;
    r[2] = (acc[2] + bflo(sv.y) * sc) * dn; r[3] = (acc[3] + bfhi(sv.y) * sc) * dn;
    r[4] = (acc[4] + bflo(sv.z) * sc) * dn; r[5] = (acc[5] + bfhi(sv.z) * sc) * dn;
    r[6] = (acc[6] + bflo(sv.w) * sc) * dn; r[7] = (acc[7] + bfhi(sv.w) * sc) * dn;
    if (BIAS) {
      const float4* b4p = (const float4*)bias;
      float4 bA = b4p[fq * 2], bB = b4p[fq * 2 + 1];
      r[0] += bA.x; r[1] += bA.y; r[2] += bA.z; r[3] += bA.w;
      r[4] += bB.x; r[5] += bB.y; r[6] += bB.z; r[7] += bB.w;
    }
    if (RELU) {
#pragma unroll
      for (int i = 0; i < 8; ++i) r[i] = fmaxf(r[i], 0.f);
    }
    uint4 o;
    o.x = pack2(r[0], r[1]); o.y = pack2(r[2], r[3]);
    o.z = pack2(r[4], r[5]); o.w = pack2(r[6], r[7]);
    out[(size_t)n * 8 + fq] = o;
  }
}

// per-graph segmented sum over sorted batch; input flat [NN][64]
__global__ void k_pool(const ushort* __restrict__ agg4, const int* __restrict__ gstart,
                       float* __restrict__ P) {
  __shared__ float part[4][GH];
  int g = blockIdx.x;
  int f = threadIdx.x & 63, r = threadIdx.x >> 6;
  int a = gstart[g], b = gstart[g + 1];
  float acc = 0.f;
  for (int n = a + r; n < b; n += 4)
    acc += __uint_as_float(((uint32_t)agg4[(size_t)n * GH + f]) << 16);
  part[r][f] = acc;
  __syncthreads();
  if (r == 0) P[(size_t)g * GH + f] = part[0][f] + part[1][f] + part[2][f] + part[3][f];
}

__global__ void k_head(const float* __restrict__ P, const int* __restrict__ gstart,
                       const float* __restrict__ W4, const float* __restrict__ b4,
                       float* __restrict__ out) {
  int g = blockIdx.x;
  int lane = threadIdx.x;  // 64
  float c = fmaxf((float)(gstart[g + 1] - gstart[g]), 1.0f);
  float p = P[(size_t)g * GH + lane] / c;
  float t[GOUT];
#pragma unroll
  for (int j = 0; j < GOUT; ++j) {
    float r = p * W4[lane * GOUT + j];
#pragma unroll
    for (int off = 1; off < 64; off <<= 1) r += __shfl_xor(r, off);
    t[j] = r + b4[j];
  }
  if (lane == 0) {
    float mx = -1e30f;
#pragma unroll
    for (int j = 0; j < GOUT; ++j) mx = fmaxf(mx, t[j]);
    float sum = 0.f;
#pragma unroll
    for (int j = 0; j < GOUT; ++j) sum += expf(t[j] - mx);
    float lse = mx + logf(sum);
#pragma unroll
    for (int j = 0; j < GOUT; ++j) out[(size_t)g * GOUT + j] = t[j] - lse;
  }
}

static inline int cdiv(long a, long b) { return (int)((a + b - 1) / b); }

extern "C" void kernel_launch(void* const* d_in, const int* in_sizes, int n_in,
                              void* d_out, int out_size, void* d_ws, size_t ws_size,
                              hipStream_t stream) {
  const float* x  = (const float*)d_in[0];
  const int*   ei = (const int*)d_in[1];
  const int*   bt = (const int*)d_in[2];
  const float* W1 = (const float*)d_in[3];
  const float* b1 = (const float*)d_in[4];
  const float* W2 = (const float*)d_in[5];
  const float* b2 = (const float*)d_in[6];
  const float* W3 = (const float*)d_in[7];
  const float* b3 = (const float*)d_in[8];
  const float* W4 = (const float*)d_in[9];
  const float* b4 = (const float*)d_in[10];
  float* out = (float*)d_out;

  ushort* HP   = (ushort*)d_ws;                       // NN*64 bf16
  ushort* ACT  = HP + (size_t)NN * GH;                // NN*64 bf16
  float* dinv  = (float*)(ACT + (size_t)NN * GH);     // NN
  float* P     = dinv + NN;                           // NG*64
  int* gstart  = (int*)(P + (size_t)NG * GH);         // NG+1
  int* deg     = gstart + NG + 3;                     // NN
  int* pref    = deg + NN;                            // NN
  int* rowptr  = pref + NN;                           // NN+1
  int* cursor  = rowptr + NN + 1;                     // NN
  int* bsum    = cursor + NN;                         // NB
  int* esrc    = bsum + ((NB + 3) & ~3);              // NE

  const int* row = ei;        // edge_index[0] = source
  const int* col = ei + NE;   // edge_index[1] = target (aggregate here)

  // --- CSR build + dinv + graph starts ---
  k_zero_i<<<cdiv(NN, TPB), TPB, 0, stream>>>(deg, NN);
  k_hist<<<cdiv(NE, TPB), TPB, 0, stream>>>(col, deg);
  k_dinv<<<cdiv(NN, TPB), TPB, 0, stream>>>(deg, dinv);
  k_gstart<<<cdiv(NG + 1, TPB), TPB, 0, stream>>>(bt, gstart);
  k_scan1<<<NB, TPB, 0, stream>>>(deg, pref, bsum);
  k_scan2<<<1, TPB, 0, stream>>>(bsum);
  k_scan3<<<cdiv(NN + 1, TPB), TPB, 0, stream>>>(pref, bsum, rowptr, cursor);
  k_scatter_p<<<8 * SPB, TPB, 0, stream>>>(row, col, cursor, esrc);

  const int gridN = cdiv(NN, TPB / 64);

  // --- layer 1 ---
  k_mm1<<<MMBLK, TPB, 0, stream>>>(x, W1, dinv, HP);
  k_agg<true, false, true><<<gridN, TPB, 0, stream>>>(rowptr, esrc, dinv, (const uint4*)HP, b1, (uint4*)ACT);
  // --- layer 2 ---
  k_mmh<<<MMBLK, TPB, 0, stream>>>(ACT, W2, dinv, HP);
  k_agg<true, false, true><<<gridN, TPB, 0, stream>>>(rowptr, esrc, dinv, (const uint4*)HP, b2, (uint4*)ACT);
  // --- layer 3 ---
  k_mmh<<<MMBLK, TPB, 0, stream>>>(ACT, W3, dinv, HP);
  k_agg<true, false, true><<<gridN, TPB, 0, stream>>>(rowptr, esrc, dinv, (const uint4*)HP, b3, (uint4*)ACT);
  // --- layer 4 (algebraic swap): AGG4 = Â·H3 into HP, no bias/relu ---
  k_agg<false, true, false><<<gridN, TPB, 0, stream>>>(rowptr, esrc, dinv, (const uint4*)ACT, nullptr, (uint4*)HP);

  // --- pool + head ---
  k_pool<<<NG, TPB, 0, stream>>>(HP, gstart, P);
  k_head<<<NG, 64, 0, stream>>>(P, gstart, W4, b4, out);
}